// Round 3
// baseline (19466.508 us; speedup 1.0000x reference)
//
#include <hip/hip_runtime.h>
#include <hip/hip_bf16.h>

// ---------------------------------------------------------------------------
// Transformer block on MI355X. Shapes fixed by the reference:
//   B=2, T=2048, H=2048, QH=16, KH=8, D=128, F=8192, M=B*T=4096
// Outputs concatenated in d_out as FLOAT32 (reference tuple dtypes: x f32,
// k f32 (rope output), v bf16 -> harness flattens at f32):
//   x [B,T,H] | k [B,T,KH,D] | v [B,T,KH,D]
// Workspace: 48 MB (xnorm | qbuf | kbuf | vbuf, bf16 staging for attention).
// ---------------------------------------------------------------------------

#define Bc  2
#define Tc  2048
#define Hc  2048
#define QHc 16
#define KHc 8
#define Dc  128
#define Fc  8192
#define Mc  (Bc*Tc)          // 4096 rows
#define FCHUNK 2048          // MLP F-chunk (4 chunks)
#define EPSc 1e-6f
#define MASKVAL (-1e30f)

typedef __bf16  bf16x8 __attribute__((ext_vector_type(8)));
typedef short   short8 __attribute__((ext_vector_type(8)));
typedef float   f32x4  __attribute__((ext_vector_type(4)));

// ---------------- reductions -------------------------------------------------
__device__ __forceinline__ float waveReduceSum(float v) {
    for (int off = 32; off > 0; off >>= 1) v += __shfl_down(v, off, 64);
    return v;
}
__device__ __forceinline__ float waveReduceMax(float v) {
    for (int off = 32; off > 0; off >>= 1) v = fmaxf(v, __shfl_down(v, off, 64));
    return v;
}

// ---------------- RMSNorm over f32 rows -> bf16 ------------------------------
// one 256-thread block per row
__global__ __launch_bounds__(256) void rmsnorm_f32_kernel(
    const float* __restrict__ in, const float* __restrict__ gamma,
    __hip_bfloat16* __restrict__ out, int width)
{
    const int row = blockIdx.x;
    const float* r = in + (size_t)row * width;
    float ss = 0.f;
    for (int i = threadIdx.x; i < width; i += 256) { float v = r[i]; ss += v * v; }
    ss = waveReduceSum(ss);
    __shared__ float red[4];
    if ((threadIdx.x & 63) == 0) red[threadIdx.x >> 6] = ss;
    __syncthreads();
    const float tot = red[0] + red[1] + red[2] + red[3];
    const float inv = 1.0f / sqrtf(tot / (float)width + EPSc);
    __hip_bfloat16* o = out + (size_t)row * width;
    for (int i = threadIdx.x; i < width; i += 256)
        o[i] = __float2bfloat16(gamma[i] * r[i] * inv);
}

// ---------------- fused per-head RMSNorm (D=128) + RoPE ----------------------
// one 128-thread block per (b,t,head) row; in/out may alias.
// outB: bf16 rope result (for attention use). outF (optional): raw f32 rope
// result (the reference's k output dtype is f32 — rope is bf16*f32 math).
__global__ __launch_bounds__(128) void qknorm_rope_kernel(
    const __hip_bfloat16* in, const float* __restrict__ gamma,
    const float* __restrict__ sinp, const float* __restrict__ cosp,
    __hip_bfloat16* outB, float* outF, int heads)
{
    const int row = blockIdx.x;            // (b*T + t)*heads + h
    const int bt  = row / heads;           // b*T + t
    const int d   = threadIdx.x;           // 0..127
    const float v = __bfloat162float(in[(size_t)row * Dc + d]);
    float ss = waveReduceSum(v * v);
    __shared__ float red[2];
    __shared__ float nrm[Dc];
    if ((d & 63) == 0) red[d >> 6] = ss;
    __syncthreads();
    const float rms = sqrtf((red[0] + red[1]) * (1.0f / (float)Dc) + EPSc);
    // reference rounds rmsnorm output to bf16 BEFORE rope
    const float xn = __bfloat162float(__float2bfloat16(gamma[d] * v / rms));
    nrm[d] = xn;
    __syncthreads();
    float res;
    if (d < 64) {
        const float s = sinp[(size_t)bt * 64 + d];
        const float c = cosp[(size_t)bt * 64 + d];
        res = nrm[d] * c - nrm[d + 64] * s;
    } else {
        const float s = sinp[(size_t)bt * 64 + (d - 64)];
        const float c = cosp[(size_t)bt * 64 + (d - 64)];
        res = nrm[d] * c + nrm[d - 64] * s;
    }
    outB[(size_t)row * Dc + d] = __float2bfloat16(res);
    if (outF) outF[(size_t)row * Dc + d] = res;   // un-rounded f32 (ref k dtype)
}

// ---------------- bf16 MFMA GEMM: C[M,N] = A[M,K](bf16) @ Bw[K,N](f32->bf16) -
// A row stride = K; Bw row stride = ldb (allows column-chunked weights).
// 128x128 tile, BK=32; 4 waves of 64x64 (4x4 of 16x16x32 MFMA).
// Epilogue modes:
//   0: outB = bf16(acc)
//   1: outF = resid + f32(bf16(acc))      (f32; outF may alias resid)
//   3: outB = bf16( bf16(silu(gmul)) * bf16(acc) )   (gmul may alias outB)
//   4: b = bf16(acc); outB = b; outF = f32(b)        (dual write, e.g. v)
__global__ __launch_bounds__(256) void gemm_kernel(
    const __hip_bfloat16* __restrict__ A, const float* __restrict__ Bw,
    __hip_bfloat16* outB, float* outF, const float* resid,
    const __hip_bfloat16* gmul, int M, int N, int K, int ldb, int mode)
{
    __shared__ __hip_bfloat16 As[128][32];      // [m][k] row-major, 8 KB
    __shared__ __hip_bfloat16 Bs[128][40];      // [n][k] (+8 pad), 10 KB

    const int tid  = threadIdx.x;
    const int lane = tid & 63;
    const int wave = tid >> 6;
    const int l15  = lane & 15;
    const int quad = lane >> 4;          // 0..3
    const int q8   = quad * 8;           // k-offset of fragment
    const int wm   = wave >> 1;          // 0..1
    const int wn   = wave & 1;           // 0..1
    const int m0   = blockIdx.y * 128;
    const int n0   = blockIdx.x * 128;

    f32x4 acc[4][4];
    const f32x4 zero = {0.f, 0.f, 0.f, 0.f};
    for (int i = 0; i < 4; ++i)
        for (int j = 0; j < 4; ++j) acc[i][j] = zero;

    const int nK = K >> 5;               // K / 32
    for (int kt = 0; kt < nK; ++kt) {
        const int k0 = kt << 5;
        __syncthreads();
        // ---- stage A: 128x32 bf16, vectorized 16B loads ---------------------
        for (int vv = 0; vv < 2; ++vv) {
            const int vi  = vv * 256 + tid;      // 0..511
            const int row = vi >> 2;
            const int col = (vi & 3) * 8;
            *(short8*)(&As[row][col]) =
                *(const short8*)(A + (size_t)(m0 + row) * K + k0 + col);
        }
        // ---- stage B: 32x128 f32 -> bf16, transposed into Bs[n][k] ----------
        {
            const int n  = tid & 127;
            const int kk = tid >> 7;             // 0 or 1
            const float* bp = Bw + (size_t)k0 * ldb + n0 + n;
            for (int p = 0; p < 16; ++p) {
                const int k = p * 2 + kk;
                Bs[n][k] = __float2bfloat16(bp[(size_t)k * ldb]);
            }
        }
        __syncthreads();
        // ---- fragments + MFMA ----------------------------------------------
        bf16x8 af[4], bfv[4];
        for (int mt = 0; mt < 4; ++mt)
            af[mt] = *reinterpret_cast<const bf16x8*>(&As[wm * 64 + mt * 16 + l15][q8]);
        for (int nt = 0; nt < 4; ++nt)
            bfv[nt] = *reinterpret_cast<const bf16x8*>(&Bs[wn * 64 + nt * 16 + l15][q8]);
        for (int mt = 0; mt < 4; ++mt)
            for (int nt = 0; nt < 4; ++nt)
                acc[mt][nt] = __builtin_amdgcn_mfma_f32_16x16x32_bf16(
                    af[mt], bfv[nt], acc[mt][nt], 0, 0, 0);
    }

    // ---- epilogue: D layout col=lane&15, row=quad*4+reg ---------------------
    for (int mt = 0; mt < 4; ++mt) {
        for (int nt = 0; nt < 4; ++nt) {
            const f32x4 a  = acc[mt][nt];
            const int col  = n0 + wn * 64 + nt * 16 + l15;
            const int rowb = m0 + wm * 64 + mt * 16 + quad * 4;
            for (int r = 0; r < 4; ++r) {
                const size_t idx = (size_t)(rowb + r) * N + col;
                const float val = a[r];
                if (mode == 0) {
                    outB[idx] = __float2bfloat16(val);
                } else if (mode == 1) {
                    // reference: residual + bf16 matmul result, kept in f32
                    outF[idx] = resid[idx] +
                                __bfloat162float(__float2bfloat16(val));
                } else if (mode == 3) {
                    // y = silu(g) * u with reference rounding points (all bf16)
                    const float g = __bfloat162float(gmul[idx]);
                    const float sil = __bfloat162float(
                        __float2bfloat16(g / (1.f + __expf(-g))));
                    const float u = __bfloat162float(__float2bfloat16(val));
                    outB[idx] = __float2bfloat16(sil * u);
                } else { // mode 4: dual write (bf16 staging + f32 output)
                    const __hip_bfloat16 b = __float2bfloat16(val);
                    outB[idx] = b;
                    outF[idx] = __bfloat162float(b);
                }
            }
        }
    }
}

// ---------------- attention: one block per (b, h, q_row) ---------------------
// scores row in LDS, exact reference semantics (mask -> -1e30, softmax w/ max)
__global__ __launch_bounds__(256) void attn_kernel(
    const __hip_bfloat16* q,                // [B,T,QH,D] roped (bf16)
    const __hip_bfloat16* __restrict__ k,   // [B,T,KH,D] roped (bf16)
    const __hip_bfloat16* __restrict__ v,   // [B,T,KH,D] (bf16)
    const int* __restrict__ mask,           // [B,T]
    __hip_bfloat16* out)                    // [B,T,QH,D] (may alias q)
{
    __shared__ float sArr[Tc];
    __shared__ float qv[Dc];
    __shared__ float oacc[256];
    __shared__ float redm[4], redl[4];

    const int tq = blockIdx.x;
    const int bh = blockIdx.y;
    const int b  = bh >> 4;          // / QH
    const int h  = bh & 15;          // % QH
    const int kh = h >> 1;           // GQA: q head h uses k/v head h/2
    const int tid = threadIdx.x;

    const size_t qoff = (((size_t)(b * Tc + tq)) * QHc + h) * Dc;
    if (tid < Dc) qv[tid] = __bfloat162float(q[qoff + tid]);
    const bool qm = (mask[b * Tc + tq] != 0);
    __syncthreads();

    const float scale = 0.08838834764831845f;  // 1/sqrt(128)

    // phase A: scores (invalid -> -1e30)
    for (int kp = tid; kp < Tc; kp += 256) {
        float s = MASKVAL;
        if (qm && kp <= tq && mask[b * Tc + kp] != 0) {
            const __hip_bfloat162* kr = (const __hip_bfloat162*)
                (k + (((size_t)(b * Tc + kp)) * KHc + kh) * Dc);
            float accd = 0.f;
            for (int j = 0; j < 64; ++j) {
                const float2 f = __bfloat1622float2(kr[j]);
                accd += qv[2 * j] * f.x + qv[2 * j + 1] * f.y;
            }
            s = accd * scale;
        }
        sArr[kp] = s;
    }
    __syncthreads();

    // phase B: softmax (max, exp, sum); p beyond causal limit underflows to 0
    float mloc = MASKVAL;
    for (int kp = tid; kp < Tc; kp += 256) mloc = fmaxf(mloc, sArr[kp]);
    mloc = waveReduceMax(mloc);
    if ((tid & 63) == 0) redm[tid >> 6] = mloc;
    __syncthreads();
    const float mm = fmaxf(fmaxf(redm[0], redm[1]), fmaxf(redm[2], redm[3]));
    float lloc = 0.f;
    for (int kp = tid; kp < Tc; kp += 256) {
        const float p = __expf(sArr[kp] - mm);
        sArr[kp] = p;
        lloc += p;
    }
    lloc = waveReduceSum(lloc);
    if ((tid & 63) == 0) redl[tid >> 6] = lloc;
    __syncthreads();
    const float l = redl[0] + redl[1] + redl[2] + redl[3];

    // phase C: o = (P @ V) / l ; fixed 2-way k-split (p is exactly 0 past tq)
    const int d    = tid & 127;
    const int half = tid >> 7;
    float acc = 0.f;
    const int k0 = half * (Tc / 2);
    for (int kp = k0; kp < k0 + Tc / 2; ++kp)
        acc += sArr[kp] * __bfloat162float(
            v[(((size_t)(b * Tc + kp)) * KHc + kh) * Dc + d]);
    oacc[tid] = acc;
    __syncthreads();
    if (tid < Dc) {
        const float o = (oacc[tid] + oacc[tid + 128]) / l;
        out[qoff + tid] = __float2bfloat16(o);
    }
}

// ---------------------------------------------------------------------------
extern "C" void kernel_launch(void* const* d_in, const int* in_sizes, int n_in,
                              void* d_out, int out_size, void* d_ws, size_t ws_size,
                              hipStream_t stream) {
    const float* x          = (const float*)d_in[0];
    const float* sinp       = (const float*)d_in[1];
    const float* cosp       = (const float*)d_in[2];
    const int*   token_mask = (const int*)d_in[3];
    // d_in[4] = layer_id (unused)
    const float* pre_gamma  = (const float*)d_in[5];
    const float* wq         = (const float*)d_in[6];
    const float* wk         = (const float*)d_in[7];
    const float* wv         = (const float*)d_in[8];
    const float* q_gamma    = (const float*)d_in[9];
    const float* k_gamma    = (const float*)d_in[10];
    const float* wo         = (const float*)d_in[11];
    const float* post_gamma = (const float*)d_in[12];
    const float* wg         = (const float*)d_in[13];
    const float* wu         = (const float*)d_in[14];
    const float* wd         = (const float*)d_in[15];

    // d_out sections, ALL FLOAT32: x | k | v
    float* outx = (float*)d_out;                                 // 8,388,608 el
    float* outk = outx + (size_t)Bc * Tc * Hc;                   // 4,194,304 el
    float* outv = outk + (size_t)Bc * Tc * KHc * Dc;             // 4,194,304 el

    // workspace layout (bytes) — total 50,331,648 (48 MB)
    char* w = (char*)d_ws;
    __hip_bfloat16* xnorm = (__hip_bfloat16*)(w);                 // 16.78 MB
    __hip_bfloat16* qbuf  = (__hip_bfloat16*)(w + 16777216);      // 16.78 MB
    __hip_bfloat16* kbuf  = (__hip_bfloat16*)(w + 33554432);      //  8.39 MB
    __hip_bfloat16* vbuf  = (__hip_bfloat16*)(w + 41943040);      //  8.39 MB
    __hip_bfloat16* Gtmp  = qbuf;   // reused after attention+wo consume qbuf

    // 1. pre-RMSNorm: x (f32) -> xnorm (bf16)
    rmsnorm_f32_kernel<<<Mc, 256, 0, stream>>>(x, pre_gamma, xnorm, Hc);

    // 2-4. QKV projections (v: dual-write bf16 staging + f32 output)
    gemm_kernel<<<dim3(Hc/128, Mc/128), 256, 0, stream>>>(
        xnorm, wq, qbuf, nullptr, nullptr, nullptr, Mc, Hc, Hc, Hc, 0);
    gemm_kernel<<<dim3((KHc*Dc)/128, Mc/128), 256, 0, stream>>>(
        xnorm, wk, kbuf, nullptr, nullptr, nullptr, Mc, KHc*Dc, Hc, KHc*Dc, 0);
    gemm_kernel<<<dim3((KHc*Dc)/128, Mc/128), 256, 0, stream>>>(
        xnorm, wv, vbuf, outv, nullptr, nullptr, Mc, KHc*Dc, Hc, KHc*Dc, 4);

    // 5-6. per-head RMSNorm + RoPE (q in place; k also emits raw f32 to d_out)
    qknorm_rope_kernel<<<Mc*QHc, 128, 0, stream>>>(
        qbuf, q_gamma, sinp, cosp, qbuf, nullptr, QHc);
    qknorm_rope_kernel<<<Mc*KHc, 128, 0, stream>>>(
        kbuf, k_gamma, sinp, cosp, kbuf, outk, KHc);

    // 7. attention (bf16 in ws; writes o in place over qbuf)
    attn_kernel<<<dim3(Tc, Bc*QHc), 256, 0, stream>>>(
        qbuf, kbuf, vbuf, token_mask, qbuf);

    // 8. wo projection + residual -> outx (f32, in d_out)
    gemm_kernel<<<dim3(Hc/128, Mc/128), 256, 0, stream>>>(
        qbuf, wo, nullptr, outx, x, nullptr, Mc, Hc, Hc, Hc, 1);

    // 9. post-RMSNorm: outx -> xnorm (bf16)
    rmsnorm_f32_kernel<<<Mc, 256, 0, stream>>>(outx, post_gamma, xnorm, Hc);

    // 10. MLP in 4 F-chunks of 2048; g/u tile reuses qbuf; y@wd accumulates
    //     into outx (f32 residual adds, matching reference rounding closely)
    for (int c = 0; c < 4; ++c) {
        const float* wg_c = wg + (size_t)c * FCHUNK;           // column chunk
        const float* wu_c = wu + (size_t)c * FCHUNK;           // column chunk
        const float* wd_c = wd + (size_t)c * FCHUNK * Hc;      // row chunk
        // g_c = bf16(xnorm @ wg_c)
        gemm_kernel<<<dim3(FCHUNK/128, Mc/128), 256, 0, stream>>>(
            xnorm, wg_c, Gtmp, nullptr, nullptr, nullptr, Mc, FCHUNK, Hc, Fc, 0);
        // y_c = bf16(silu(g_c)) * bf16(xnorm @ wu_c)
        gemm_kernel<<<dim3(FCHUNK/128, Mc/128), 256, 0, stream>>>(
            xnorm, wu_c, Gtmp, nullptr, nullptr, Gtmp, Mc, FCHUNK, Hc, Fc, 3);
        // outx += y_c @ wd_c
        gemm_kernel<<<dim3(Hc/128, Mc/128), 256, 0, stream>>>(
            Gtmp, wd_c, nullptr, outx, outx, nullptr, Mc, Hc, FCHUNK, Hc, 1);
    }
}

// Round 4
// 7120.162 us; speedup vs baseline: 2.7340x; 2.7340x over previous
//
#include <hip/hip_runtime.h>
#include <hip/hip_bf16.h>

// ---------------------------------------------------------------------------
// Transformer block on MI355X. Shapes fixed by the reference:
//   B=2, T=2048, H=2048, QH=16, KH=8, D=128, F=8192, M=B*T=4096
// Outputs concatenated in d_out as FLOAT32: x | k | v
// Round 3 -> 4: scalar attention (12.8 ms, MfmaUtil=0) replaced by MFMA
// flash attention (predicted ~0.1-0.3 ms).
// ---------------------------------------------------------------------------

#define Bc  2
#define Tc  2048
#define Hc  2048
#define QHc 16
#define KHc 8
#define Dc  128
#define Fc  8192
#define Mc  (Bc*Tc)          // 4096 rows
#define FCHUNK 2048          // MLP F-chunk (4 chunks)
#define EPSc 1e-6f
#define MASKVAL (-1e30f)

typedef __bf16  bf16x8 __attribute__((ext_vector_type(8)));
typedef short   short8 __attribute__((ext_vector_type(8)));
typedef float   f32x4  __attribute__((ext_vector_type(4)));

// ---------------- reductions -------------------------------------------------
__device__ __forceinline__ float waveReduceSum(float v) {
    for (int off = 32; off > 0; off >>= 1) v += __shfl_down(v, off, 64);
    return v;
}

// ---------------- RMSNorm over f32 rows -> bf16 ------------------------------
__global__ __launch_bounds__(256) void rmsnorm_f32_kernel(
    const float* __restrict__ in, const float* __restrict__ gamma,
    __hip_bfloat16* __restrict__ out, int width)
{
    const int row = blockIdx.x;
    const float* r = in + (size_t)row * width;
    float ss = 0.f;
    for (int i = threadIdx.x; i < width; i += 256) { float v = r[i]; ss += v * v; }
    ss = waveReduceSum(ss);
    __shared__ float red[4];
    if ((threadIdx.x & 63) == 0) red[threadIdx.x >> 6] = ss;
    __syncthreads();
    const float tot = red[0] + red[1] + red[2] + red[3];
    const float inv = 1.0f / sqrtf(tot / (float)width + EPSc);
    __hip_bfloat16* o = out + (size_t)row * width;
    for (int i = threadIdx.x; i < width; i += 256)
        o[i] = __float2bfloat16(gamma[i] * r[i] * inv);
}

// ---------------- fused per-head RMSNorm (D=128) + RoPE ----------------------
__global__ __launch_bounds__(128) void qknorm_rope_kernel(
    const __hip_bfloat16* in, const float* __restrict__ gamma,
    const float* __restrict__ sinp, const float* __restrict__ cosp,
    __hip_bfloat16* outB, float* outF, int heads)
{
    const int row = blockIdx.x;            // (b*T + t)*heads + h
    const int bt  = row / heads;           // b*T + t
    const int d   = threadIdx.x;           // 0..127
    const float v = __bfloat162float(in[(size_t)row * Dc + d]);
    float ss = waveReduceSum(v * v);
    __shared__ float red[2];
    __shared__ float nrm[Dc];
    if ((d & 63) == 0) red[d >> 6] = ss;
    __syncthreads();
    const float rms = sqrtf((red[0] + red[1]) * (1.0f / (float)Dc) + EPSc);
    const float xn = __bfloat162float(__float2bfloat16(gamma[d] * v / rms));
    nrm[d] = xn;
    __syncthreads();
    float res;
    if (d < 64) {
        const float s = sinp[(size_t)bt * 64 + d];
        const float c = cosp[(size_t)bt * 64 + d];
        res = nrm[d] * c - nrm[d + 64] * s;
    } else {
        const float s = sinp[(size_t)bt * 64 + (d - 64)];
        const float c = cosp[(size_t)bt * 64 + (d - 64)];
        res = nrm[d] * c + nrm[d - 64] * s;
    }
    outB[(size_t)row * Dc + d] = __float2bfloat16(res);
    if (outF) outF[(size_t)row * Dc + d] = res;   // un-rounded f32 (ref k dtype)
}

// ---------------- bf16 MFMA GEMM (unchanged from round 3, passing) ----------
__global__ __launch_bounds__(256) void gemm_kernel(
    const __hip_bfloat16* __restrict__ A, const float* __restrict__ Bw,
    __hip_bfloat16* outB, float* outF, const float* resid,
    const __hip_bfloat16* gmul, int M, int N, int K, int ldb, int mode)
{
    __shared__ __hip_bfloat16 As[128][32];
    __shared__ __hip_bfloat16 Bs[128][40];

    const int tid  = threadIdx.x;
    const int lane = tid & 63;
    const int wave = tid >> 6;
    const int l15  = lane & 15;
    const int quad = lane >> 4;
    const int q8   = quad * 8;
    const int wm   = wave >> 1;
    const int wn   = wave & 1;
    const int m0   = blockIdx.y * 128;
    const int n0   = blockIdx.x * 128;

    f32x4 acc[4][4];
    const f32x4 zero = {0.f, 0.f, 0.f, 0.f};
    for (int i = 0; i < 4; ++i)
        for (int j = 0; j < 4; ++j) acc[i][j] = zero;

    const int nK = K >> 5;
    for (int kt = 0; kt < nK; ++kt) {
        const int k0 = kt << 5;
        __syncthreads();
        for (int vv = 0; vv < 2; ++vv) {
            const int vi  = vv * 256 + tid;
            const int row = vi >> 2;
            const int col = (vi & 3) * 8;
            *(short8*)(&As[row][col]) =
                *(const short8*)(A + (size_t)(m0 + row) * K + k0 + col);
        }
        {
            const int n  = tid & 127;
            const int kk = tid >> 7;
            const float* bp = Bw + (size_t)k0 * ldb + n0 + n;
            for (int p = 0; p < 16; ++p) {
                const int k = p * 2 + kk;
                Bs[n][k] = __float2bfloat16(bp[(size_t)k * ldb]);
            }
        }
        __syncthreads();
        bf16x8 af[4], bfv[4];
        for (int mt = 0; mt < 4; ++mt)
            af[mt] = *reinterpret_cast<const bf16x8*>(&As[wm * 64 + mt * 16 + l15][q8]);
        for (int nt = 0; nt < 4; ++nt)
            bfv[nt] = *reinterpret_cast<const bf16x8*>(&Bs[wn * 64 + nt * 16 + l15][q8]);
        for (int mt = 0; mt < 4; ++mt)
            for (int nt = 0; nt < 4; ++nt)
                acc[mt][nt] = __builtin_amdgcn_mfma_f32_16x16x32_bf16(
                    af[mt], bfv[nt], acc[mt][nt], 0, 0, 0);
    }

    for (int mt = 0; mt < 4; ++mt) {
        for (int nt = 0; nt < 4; ++nt) {
            const f32x4 a  = acc[mt][nt];
            const int col  = n0 + wn * 64 + nt * 16 + l15;
            const int rowb = m0 + wm * 64 + mt * 16 + quad * 4;
            for (int r = 0; r < 4; ++r) {
                const size_t idx = (size_t)(rowb + r) * N + col;
                const float val = a[r];
                if (mode == 0) {
                    outB[idx] = __float2bfloat16(val);
                } else if (mode == 1) {
                    outF[idx] = resid[idx] +
                                __bfloat162float(__float2bfloat16(val));
                } else if (mode == 3) {
                    const float g = __bfloat162float(gmul[idx]);
                    const float sil = __bfloat162float(
                        __float2bfloat16(g / (1.f + __expf(-g))));
                    const float u = __bfloat162float(__float2bfloat16(val));
                    outB[idx] = __float2bfloat16(sil * u);
                } else { // mode 4
                    const __hip_bfloat16 b = __float2bfloat16(val);
                    outB[idx] = b;
                    outF[idx] = __bfloat162float(b);
                }
            }
        }
    }
}

// ---------------- MFMA flash attention --------------------------------------
// one workgroup per (b, h, 64-row q-tile); 4 waves, each owns a 16-row strip.
// K-tiles of 64 iterated up to the causal diagonal; online softmax (m,l per
// row in registers); P goes through wave-private LDS to enter A-layout.
__global__ __launch_bounds__(256) void flash_attn_kernel(
    const __hip_bfloat16* q,                // [B,T,QH,D] roped bf16
    const __hip_bfloat16* __restrict__ k,   // [B,T,KH,D] roped bf16
    const __hip_bfloat16* __restrict__ v,   // [B,T,KH,D] bf16
    const int* __restrict__ mask,           // [B,T]
    __hip_bfloat16* out)                    // [B,T,QH,D] (may alias q)
{
    __shared__ unsigned short Ks[64][136];   // [kv][d]  +8 pad, 17.0 KB
    __shared__ unsigned short Vs[128][72];   // [d][kv]  +8 pad, 18.4 KB
    __shared__ unsigned short Ps[4][16][72]; // per-wave P, +8 pad, 9.2 KB
    __shared__ int msk[64];

    const int tid  = threadIdx.x;
    const int lane = tid & 63;
    const int wave = tid >> 6;
    const int l15  = lane & 15;
    const int quad = lane >> 4;
    const int q0   = blockIdx.x * 64;
    const int bh   = blockIdx.y;
    const int b    = bh >> 4;
    const int h    = bh & 15;
    const int kh   = h >> 1;                 // GQA: 2 q-heads per kv-head

    const float scale = 0.08838834764831845f;   // 1/sqrt(128)

    // Q fragments for this wave's 16-row strip (A-layout: m=l15, k=quad*8+j)
    bf16x8 qf[4];
    {
        const __hip_bfloat16* qp =
            q + (((size_t)(b * Tc + q0 + wave * 16 + l15)) * QHc + h) * Dc;
        for (int kk = 0; kk < 4; ++kk)
            qf[kk] = *(const bf16x8*)(qp + kk * 32 + quad * 8);
    }

    // online-softmax state: lane covers strip rows quad*4+r (C-layout rows)
    float mrow[4] = {MASKVAL, MASKVAL, MASKVAL, MASKVAL};
    float lrow[4] = {0.f, 0.f, 0.f, 0.f};
    f32x4 oacc[8];
    for (int i = 0; i < 8; ++i) oacc[i] = (f32x4){0.f, 0.f, 0.f, 0.f};

    const int ktmax = q0 >> 6;               // inclusive (causal)
    for (int kt = 0; kt <= ktmax; ++kt) {
        const int kvbase = kt * 64;
        __syncthreads();                     // protect LDS from prev iter
        // ---- stage K tile [64][128] -> Ks[kv][d] (16B vector copies) -------
        for (int i = 0; i < 4; ++i) {
            const int c  = i * 256 + tid;    // 0..1023 chunks of 8
            const int kv = c >> 4;
            const int d0 = (c & 15) * 8;
            *(bf16x8*)(&Ks[kv][d0]) = *(const bf16x8*)(
                k + (((size_t)(b * Tc + kvbase + kv)) * KHc + kh) * Dc + d0);
        }
        // ---- stage V tile transposed -> Vs[d][kv] --------------------------
        {
            const int kv = tid & 63;
            const int g0 = (tid >> 6) * 4;
            for (int g = g0; g < g0 + 4; ++g) {
                const int d0 = g * 8;
                const short8 tmp = *(const short8*)(
                    v + (((size_t)(b * Tc + kvbase + kv)) * KHc + kh) * Dc + d0);
                for (int j = 0; j < 8; ++j)
                    Vs[d0 + j][kv] = (unsigned short)tmp[j];
            }
        }
        if (tid < 64) msk[tid] = mask[b * Tc + kvbase + tid];
        __syncthreads();

        // ---- S = Q K^T (16 MFMA), rows=strip rows, cols=kv within tile -----
        f32x4 sacc[4];
        for (int nt = 0; nt < 4; ++nt) sacc[nt] = (f32x4){0.f, 0.f, 0.f, 0.f};
        for (int nt = 0; nt < 4; ++nt)
            for (int kk = 0; kk < 4; ++kk) {
                const bf16x8 kf = *(const bf16x8*)(&Ks[nt * 16 + l15][kk * 32 + quad * 8]);
                sacc[nt] = __builtin_amdgcn_mfma_f32_16x16x32_bf16(
                    qf[kk], kf, sacc[nt], 0, 0, 0);
            }

        // ---- scale + mask + tile row-max -----------------------------------
        float tmax[4] = {MASKVAL, MASKVAL, MASKVAL, MASKVAL};
        for (int nt = 0; nt < 4; ++nt) {
            const int kvpos  = kvbase + nt * 16 + l15;
            const bool kvld  = (msk[nt * 16 + l15] != 0);
            for (int r = 0; r < 4; ++r) {
                const int qr = q0 + wave * 16 + quad * 4 + r;
                float s = sacc[nt][r] * scale;
                s = (kvld && kvpos <= qr) ? s : MASKVAL;
                sacc[nt][r] = s;
                tmax[r] = fmaxf(tmax[r], s);
            }
        }
        // butterfly max across the 16 lanes of each column group
        for (int r = 0; r < 4; ++r)
            for (int off = 1; off < 16; off <<= 1)
                tmax[r] = fmaxf(tmax[r], __shfl_xor(tmax[r], off, 64));

        // ---- online-softmax update -----------------------------------------
        float alpha[4];
        for (int r = 0; r < 4; ++r) {
            const float mnew = fmaxf(mrow[r], tmax[r]);
            alpha[r] = __expf(mrow[r] - mnew);
            mrow[r]  = mnew;
        }
        float tsum[4] = {0.f, 0.f, 0.f, 0.f};
        for (int nt = 0; nt < 4; ++nt)
            for (int r = 0; r < 4; ++r) {
                const float p = __expf(sacc[nt][r] - mrow[r]);
                sacc[nt][r] = p;
                tsum[r] += p;
            }
        for (int r = 0; r < 4; ++r)
            for (int off = 1; off < 16; off <<= 1)
                tsum[r] += __shfl_xor(tsum[r], off, 64);
        for (int r = 0; r < 4; ++r)
            lrow[r] = lrow[r] * alpha[r] + tsum[r];

        // ---- P -> wave-private LDS (C-layout write, A-layout read) ---------
        for (int nt = 0; nt < 4; ++nt)
            for (int r = 0; r < 4; ++r) {
                const __hip_bfloat16 pb = __float2bfloat16(sacc[nt][r]);
                Ps[wave][quad * 4 + r][nt * 16 + l15] =
                    *(const unsigned short*)&pb;
            }
        __syncthreads();   // orders Ps writes before reads (uniform ctrl flow)

        // ---- O = O*alpha + P @ V (16 MFMA) ---------------------------------
        for (int ntd = 0; ntd < 8; ++ntd)
            for (int r = 0; r < 4; ++r) oacc[ntd][r] *= alpha[r];
        bf16x8 pa[2];
        for (int kk2 = 0; kk2 < 2; ++kk2)
            pa[kk2] = *(const bf16x8*)(&Ps[wave][l15][kk2 * 32 + quad * 8]);
        for (int ntd = 0; ntd < 8; ++ntd)
            for (int kk2 = 0; kk2 < 2; ++kk2) {
                const bf16x8 vf = *(const bf16x8*)(
                    &Vs[ntd * 16 + l15][kk2 * 32 + quad * 8]);
                oacc[ntd] = __builtin_amdgcn_mfma_f32_16x16x32_bf16(
                    pa[kk2], vf, oacc[ntd], 0, 0, 0);
            }
    }

    // ---- epilogue: o /= l; C-layout rows quad*4+r, cols ntd*16+l15 ----------
    for (int ntd = 0; ntd < 8; ++ntd)
        for (int r = 0; r < 4; ++r) {
            const float li = lrow[r];
            const float o  = (li > 0.f) ? oacc[ntd][r] / li : 0.f;
            const int qr   = q0 + wave * 16 + quad * 4 + r;
            out[(((size_t)(b * Tc + qr)) * QHc + h) * Dc + ntd * 16 + l15] =
                __float2bfloat16(o);
        }
}

// ---------------------------------------------------------------------------
extern "C" void kernel_launch(void* const* d_in, const int* in_sizes, int n_in,
                              void* d_out, int out_size, void* d_ws, size_t ws_size,
                              hipStream_t stream) {
    const float* x          = (const float*)d_in[0];
    const float* sinp       = (const float*)d_in[1];
    const float* cosp       = (const float*)d_in[2];
    const int*   token_mask = (const int*)d_in[3];
    const float* pre_gamma  = (const float*)d_in[5];
    const float* wq         = (const float*)d_in[6];
    const float* wk         = (const float*)d_in[7];
    const float* wv         = (const float*)d_in[8];
    const float* q_gamma    = (const float*)d_in[9];
    const float* k_gamma    = (const float*)d_in[10];
    const float* wo         = (const float*)d_in[11];
    const float* post_gamma = (const float*)d_in[12];
    const float* wg         = (const float*)d_in[13];
    const float* wu         = (const float*)d_in[14];
    const float* wd         = (const float*)d_in[15];

    // d_out sections, ALL FLOAT32: x | k | v
    float* outx = (float*)d_out;
    float* outk = outx + (size_t)Bc * Tc * Hc;
    float* outv = outk + (size_t)Bc * Tc * KHc * Dc;

    // workspace layout (bytes) — total 50,331,648 (48 MB)
    char* w = (char*)d_ws;
    __hip_bfloat16* xnorm = (__hip_bfloat16*)(w);                 // 16.78 MB
    __hip_bfloat16* qbuf  = (__hip_bfloat16*)(w + 16777216);      // 16.78 MB
    __hip_bfloat16* kbuf  = (__hip_bfloat16*)(w + 33554432);      //  8.39 MB
    __hip_bfloat16* vbuf  = (__hip_bfloat16*)(w + 41943040);      //  8.39 MB
    __hip_bfloat16* Gtmp  = qbuf;   // reused after attention+wo consume qbuf

    // 1. pre-RMSNorm
    rmsnorm_f32_kernel<<<Mc, 256, 0, stream>>>(x, pre_gamma, xnorm, Hc);

    // 2-4. QKV projections (v: dual-write bf16 staging + f32 output)
    gemm_kernel<<<dim3(Hc/128, Mc/128), 256, 0, stream>>>(
        xnorm, wq, qbuf, nullptr, nullptr, nullptr, Mc, Hc, Hc, Hc, 0);
    gemm_kernel<<<dim3((KHc*Dc)/128, Mc/128), 256, 0, stream>>>(
        xnorm, wk, kbuf, nullptr, nullptr, nullptr, Mc, KHc*Dc, Hc, KHc*Dc, 0);
    gemm_kernel<<<dim3((KHc*Dc)/128, Mc/128), 256, 0, stream>>>(
        xnorm, wv, vbuf, outv, nullptr, nullptr, Mc, KHc*Dc, Hc, KHc*Dc, 4);

    // 5-6. per-head RMSNorm + RoPE
    qknorm_rope_kernel<<<Mc*QHc, 128, 0, stream>>>(
        qbuf, q_gamma, sinp, cosp, qbuf, nullptr, QHc);
    qknorm_rope_kernel<<<Mc*KHc, 128, 0, stream>>>(
        kbuf, k_gamma, sinp, cosp, kbuf, outk, KHc);

    // 7. MFMA flash attention (writes o in place over qbuf)
    flash_attn_kernel<<<dim3(Tc/64, Bc*QHc), 256, 0, stream>>>(
        qbuf, kbuf, vbuf, token_mask, qbuf);

    // 8. wo projection + residual -> outx (f32, in d_out)
    gemm_kernel<<<dim3(Hc/128, Mc/128), 256, 0, stream>>>(
        qbuf, wo, nullptr, outx, x, nullptr, Mc, Hc, Hc, Hc, 1);

    // 9. post-RMSNorm
    rmsnorm_f32_kernel<<<Mc, 256, 0, stream>>>(outx, post_gamma, xnorm, Hc);

    // 10. MLP in 4 F-chunks of 2048
    for (int c = 0; c < 4; ++c) {
        const float* wg_c = wg + (size_t)c * FCHUNK;
        const float* wu_c = wu + (size_t)c * FCHUNK;
        const float* wd_c = wd + (size_t)c * FCHUNK * Hc;
        gemm_kernel<<<dim3(FCHUNK/128, Mc/128), 256, 0, stream>>>(
            xnorm, wg_c, Gtmp, nullptr, nullptr, nullptr, Mc, FCHUNK, Hc, Fc, 0);
        gemm_kernel<<<dim3(FCHUNK/128, Mc/128), 256, 0, stream>>>(
            xnorm, wu_c, Gtmp, nullptr, nullptr, Gtmp, Mc, FCHUNK, Hc, Fc, 3);
        gemm_kernel<<<dim3(Hc/128, Mc/128), 256, 0, stream>>>(
            Gtmp, wd_c, nullptr, outx, outx, nullptr, Mc, Hc, FCHUNK, Hc, 1);
    }
}

// Round 5
// 6006.572 us; speedup vs baseline: 3.2409x; 1.1854x over previous
//
#include <hip/hip_runtime.h>
#include <hip/hip_bf16.h>

// ---------------------------------------------------------------------------
// Transformer block on MI355X. B=2, T=2048, H=2048, QH=16, KH=8, D=128, F=8192
// Outputs concatenated in d_out as FLOAT32: x | k | v
// Round 4 -> 5: GEMMs were memory-bound on f32 weights (54% HBM, MfmaUtil 3%).
// Now: weights converted once per launch to bf16 [N][K] in ws, GEMM restructured
// to m97-style global_load_lds staging. Fallback to old path if ws too small.
// ---------------------------------------------------------------------------

#define Bc  2
#define Tc  2048
#define Hc  2048
#define QHc 16
#define KHc 8
#define Dc  128
#define Fc  8192
#define Mc  (Bc*Tc)          // 4096 rows
#define FCHUNK 2048          // MLP F-chunk (4 chunks)
#define EPSc 1e-6f
#define MASKVAL (-1e30f)

typedef __bf16  bf16x8 __attribute__((ext_vector_type(8)));
typedef short   short8 __attribute__((ext_vector_type(8)));
typedef float   f32x4  __attribute__((ext_vector_type(4)));

// ---------------- reductions -------------------------------------------------
__device__ __forceinline__ float waveReduceSum(float v) {
    for (int off = 32; off > 0; off >>= 1) v += __shfl_down(v, off, 64);
    return v;
}

// ---------------- async global->LDS 16B helper -------------------------------
__device__ __forceinline__ void load_lds_16(const __hip_bfloat16* g,
                                            __hip_bfloat16* l) {
    __builtin_amdgcn_global_load_lds(
        (const __attribute__((address_space(1))) void*)g,
        (__attribute__((address_space(3))) void*)l, 16, 0, 0);
}

// ---------------- RMSNorm over f32 rows -> bf16 ------------------------------
__global__ __launch_bounds__(256) void rmsnorm_f32_kernel(
    const float* __restrict__ in, const float* __restrict__ gamma,
    __hip_bfloat16* __restrict__ out, int width)
{
    const int row = blockIdx.x;
    const float* r = in + (size_t)row * width;
    float ss = 0.f;
    for (int i = threadIdx.x; i < width; i += 256) { float v = r[i]; ss += v * v; }
    ss = waveReduceSum(ss);
    __shared__ float red[4];
    if ((threadIdx.x & 63) == 0) red[threadIdx.x >> 6] = ss;
    __syncthreads();
    const float tot = red[0] + red[1] + red[2] + red[3];
    const float inv = 1.0f / sqrtf(tot / (float)width + EPSc);
    __hip_bfloat16* o = out + (size_t)row * width;
    for (int i = threadIdx.x; i < width; i += 256)
        o[i] = __float2bfloat16(gamma[i] * r[i] * inv);
}

// ---------------- fused per-head RMSNorm (D=128) + RoPE ----------------------
__global__ __launch_bounds__(128) void qknorm_rope_kernel(
    const __hip_bfloat16* in, const float* __restrict__ gamma,
    const float* __restrict__ sinp, const float* __restrict__ cosp,
    __hip_bfloat16* outB, float* outF, int heads)
{
    const int row = blockIdx.x;            // (b*T + t)*heads + h
    const int bt  = row / heads;           // b*T + t
    const int d   = threadIdx.x;           // 0..127
    const float v = __bfloat162float(in[(size_t)row * Dc + d]);
    float ss = waveReduceSum(v * v);
    __shared__ float red[2];
    __shared__ float nrm[Dc];
    if ((d & 63) == 0) red[d >> 6] = ss;
    __syncthreads();
    const float rms = sqrtf((red[0] + red[1]) * (1.0f / (float)Dc) + EPSc);
    const float xn = __bfloat162float(__float2bfloat16(gamma[d] * v / rms));
    nrm[d] = xn;
    __syncthreads();
    float res;
    if (d < 64) {
        const float s = sinp[(size_t)bt * 64 + d];
        const float c = cosp[(size_t)bt * 64 + d];
        res = nrm[d] * c - nrm[d + 64] * s;
    } else {
        const float s = sinp[(size_t)bt * 64 + (d - 64)];
        const float c = cosp[(size_t)bt * 64 + (d - 64)];
        res = nrm[d] * c + nrm[d - 64] * s;
    }
    outB[(size_t)row * Dc + d] = __float2bfloat16(res);
    if (outF) outF[(size_t)row * Dc + d] = res;   // un-rounded f32 (ref k dtype)
}

// ---------------- weight convert+transpose: W f32[K][N] -> Wt bf16[N][K] -----
__global__ __launch_bounds__(256) void convert_transpose_kernel(
    const float* __restrict__ W, __hip_bfloat16* __restrict__ Wt, int K, int N)
{
    __shared__ float tile[32][33];
    const int tx = threadIdx.x & 31;
    const int ty = threadIdx.x >> 5;       // 0..7
    const int n0 = blockIdx.x * 32;
    const int k0 = blockIdx.y * 32;
    for (int r = 0; r < 4; ++r) {
        const int k = ty + r * 8;
        tile[k][tx] = W[(size_t)(k0 + k) * N + n0 + tx];
    }
    __syncthreads();
    for (int r = 0; r < 4; ++r) {
        const int n = ty + r * 8;
        Wt[(size_t)(n0 + n) * K + k0 + tx] = __float2bfloat16(tile[tx][n]);
    }
}

// ---------------- fast bf16 GEMM (B^T weights, global_load_lds staging) ------
// C[M,N] = A[M,K](bf16, lda) @ Bt[N,K]^T (bf16, ldt). 128x128 tile, BK=32.
// Epilogue modes as before: 0 bf16; 1 f32 resid+bf16(acc); 3 silu-mul; 4 dual.
__global__ __launch_bounds__(256) void gemm_bt_kernel(
    const __hip_bfloat16* __restrict__ A, const __hip_bfloat16* __restrict__ Bt,
    __hip_bfloat16* outB, float* outF, const float* resid,
    const __hip_bfloat16* gmul, int M, int N, int K, int lda, int ldt, int mode)
{
    __shared__ __hip_bfloat16 As[128 * 32];     // [m][k], 8 KB, no pad
    __shared__ __hip_bfloat16 Bs[128 * 32];     // [n][k], 8 KB, no pad

    const int tid  = threadIdx.x;
    const int lane = tid & 63;
    const int wave = tid >> 6;
    const int l15  = lane & 15;
    const int quad = lane >> 4;
    const int q8   = quad * 8;
    const int wm   = wave >> 1;
    const int wn   = wave & 1;
    const int m0   = blockIdx.y * 128;
    const int n0   = blockIdx.x * 128;

    // staging chunks: chunk c covers row c>>2, k-offset (c&3)*8 (16 B each)
    const int c0 = tid, c1 = tid + 256;
    const int r0 = c0 >> 2, o0 = (c0 & 3) * 8;
    const int r1 = c1 >> 2, o1 = (c1 & 3) * 8;
    const __hip_bfloat16* gA0 = A + (size_t)(m0 + r0) * lda + o0;
    const __hip_bfloat16* gA1 = A + (size_t)(m0 + r1) * lda + o1;
    const __hip_bfloat16* gB0 = Bt + (size_t)(n0 + r0) * ldt + o0;
    const __hip_bfloat16* gB1 = Bt + (size_t)(n0 + r1) * ldt + o1;

    f32x4 acc[4][4];
    const f32x4 zero = {0.f, 0.f, 0.f, 0.f};
    for (int i = 0; i < 4; ++i)
        for (int j = 0; j < 4; ++j) acc[i][j] = zero;

    for (int k0 = 0; k0 < K; k0 += 32) {
        __syncthreads();                        // protect LDS from prev reads
        load_lds_16(gA0 + k0, As + c0 * 8);
        load_lds_16(gA1 + k0, As + c1 * 8);
        load_lds_16(gB0 + k0, Bs + c0 * 8);
        load_lds_16(gB1 + k0, Bs + c1 * 8);
        __syncthreads();                        // waits vmcnt(0) -> LDS ready

        bf16x8 af[4], bfv[4];
#pragma unroll
        for (int mt = 0; mt < 4; ++mt)
            af[mt] = *reinterpret_cast<const bf16x8*>(
                As + (wm * 64 + mt * 16 + l15) * 32 + q8);
#pragma unroll
        for (int nt = 0; nt < 4; ++nt)
            bfv[nt] = *reinterpret_cast<const bf16x8*>(
                Bs + (wn * 64 + nt * 16 + l15) * 32 + q8);
#pragma unroll
        for (int mt = 0; mt < 4; ++mt)
#pragma unroll
            for (int nt = 0; nt < 4; ++nt)
                acc[mt][nt] = __builtin_amdgcn_mfma_f32_16x16x32_bf16(
                    af[mt], bfv[nt], acc[mt][nt], 0, 0, 0);
    }

    // ---- epilogue: D layout col=lane&15, row=quad*4+reg ---------------------
    for (int mt = 0; mt < 4; ++mt) {
        for (int nt = 0; nt < 4; ++nt) {
            const f32x4 a  = acc[mt][nt];
            const int col  = n0 + wn * 64 + nt * 16 + l15;
            const int rowb = m0 + wm * 64 + mt * 16 + quad * 4;
            for (int r = 0; r < 4; ++r) {
                const size_t idx = (size_t)(rowb + r) * N + col;
                const float val = a[r];
                if (mode == 0) {
                    outB[idx] = __float2bfloat16(val);
                } else if (mode == 1) {
                    outF[idx] = resid[idx] +
                                __bfloat162float(__float2bfloat16(val));
                } else if (mode == 3) {
                    const float g = __bfloat162float(gmul[idx]);
                    const float sil = __bfloat162float(
                        __float2bfloat16(g / (1.f + __expf(-g))));
                    const float u = __bfloat162float(__float2bfloat16(val));
                    outB[idx] = __float2bfloat16(sil * u);
                } else { // mode 4
                    const __hip_bfloat16 b = __float2bfloat16(val);
                    outB[idx] = b;
                    outF[idx] = __bfloat162float(b);
                }
            }
        }
    }
}

// ---------------- slow-path GEMM (round-4, f32 weights) — ws fallback --------
__global__ __launch_bounds__(256) void gemm_kernel(
    const __hip_bfloat16* __restrict__ A, const float* __restrict__ Bw,
    __hip_bfloat16* outB, float* outF, const float* resid,
    const __hip_bfloat16* gmul, int M, int N, int K, int ldb, int mode)
{
    __shared__ __hip_bfloat16 As[128][32];
    __shared__ __hip_bfloat16 Bs[128][40];

    const int tid  = threadIdx.x;
    const int lane = tid & 63;
    const int wave = tid >> 6;
    const int l15  = lane & 15;
    const int quad = lane >> 4;
    const int q8   = quad * 8;
    const int wm   = wave >> 1;
    const int wn   = wave & 1;
    const int m0   = blockIdx.y * 128;
    const int n0   = blockIdx.x * 128;

    f32x4 acc[4][4];
    const f32x4 zero = {0.f, 0.f, 0.f, 0.f};
    for (int i = 0; i < 4; ++i)
        for (int j = 0; j < 4; ++j) acc[i][j] = zero;

    const int nK = K >> 5;
    for (int kt = 0; kt < nK; ++kt) {
        const int k0 = kt << 5;
        __syncthreads();
        for (int vv = 0; vv < 2; ++vv) {
            const int vi  = vv * 256 + tid;
            const int row = vi >> 2;
            const int col = (vi & 3) * 8;
            *(short8*)(&As[row][col]) =
                *(const short8*)(A + (size_t)(m0 + row) * K + k0 + col);
        }
        {
            const int n  = tid & 127;
            const int kk = tid >> 7;
            const float* bp = Bw + (size_t)k0 * ldb + n0 + n;
            for (int p = 0; p < 16; ++p) {
                const int k = p * 2 + kk;
                Bs[n][k] = __float2bfloat16(bp[(size_t)k * ldb]);
            }
        }
        __syncthreads();
        bf16x8 af[4], bfv[4];
        for (int mt = 0; mt < 4; ++mt)
            af[mt] = *reinterpret_cast<const bf16x8*>(&As[wm * 64 + mt * 16 + l15][q8]);
        for (int nt = 0; nt < 4; ++nt)
            bfv[nt] = *reinterpret_cast<const bf16x8*>(&Bs[wn * 64 + nt * 16 + l15][q8]);
        for (int mt = 0; mt < 4; ++mt)
            for (int nt = 0; nt < 4; ++nt)
                acc[mt][nt] = __builtin_amdgcn_mfma_f32_16x16x32_bf16(
                    af[mt], bfv[nt], acc[mt][nt], 0, 0, 0);
    }

    for (int mt = 0; mt < 4; ++mt) {
        for (int nt = 0; nt < 4; ++nt) {
            const f32x4 a  = acc[mt][nt];
            const int col  = n0 + wn * 64 + nt * 16 + l15;
            const int rowb = m0 + wm * 64 + mt * 16 + quad * 4;
            for (int r = 0; r < 4; ++r) {
                const size_t idx = (size_t)(rowb + r) * N + col;
                const float val = a[r];
                if (mode == 0) {
                    outB[idx] = __float2bfloat16(val);
                } else if (mode == 1) {
                    outF[idx] = resid[idx] +
                                __bfloat162float(__float2bfloat16(val));
                } else if (mode == 3) {
                    const float g = __bfloat162float(gmul[idx]);
                    const float sil = __bfloat162float(
                        __float2bfloat16(g / (1.f + __expf(-g))));
                    const float u = __bfloat162float(__float2bfloat16(val));
                    outB[idx] = __float2bfloat16(sil * u);
                } else {
                    const __hip_bfloat16 b = __float2bfloat16(val);
                    outB[idx] = b;
                    outF[idx] = __bfloat162float(b);
                }
            }
        }
    }
}

// ---------------- MFMA flash attention (unchanged, passing) ------------------
__global__ __launch_bounds__(256) void flash_attn_kernel(
    const __hip_bfloat16* q, const __hip_bfloat16* __restrict__ k,
    const __hip_bfloat16* __restrict__ v, const int* __restrict__ mask,
    __hip_bfloat16* out)
{
    __shared__ unsigned short Ks[64][136];
    __shared__ unsigned short Vs[128][72];
    __shared__ unsigned short Ps[4][16][72];
    __shared__ int msk[64];

    const int tid  = threadIdx.x;
    const int lane = tid & 63;
    const int wave = tid >> 6;
    const int l15  = lane & 15;
    const int quad = lane >> 4;
    const int q0   = blockIdx.x * 64;
    const int bh   = blockIdx.y;
    const int b    = bh >> 4;
    const int h    = bh & 15;
    const int kh   = h >> 1;

    const float scale = 0.08838834764831845f;

    bf16x8 qf[4];
    {
        const __hip_bfloat16* qp =
            q + (((size_t)(b * Tc + q0 + wave * 16 + l15)) * QHc + h) * Dc;
        for (int kk = 0; kk < 4; ++kk)
            qf[kk] = *(const bf16x8*)(qp + kk * 32 + quad * 8);
    }

    float mrow[4] = {MASKVAL, MASKVAL, MASKVAL, MASKVAL};
    float lrow[4] = {0.f, 0.f, 0.f, 0.f};
    f32x4 oacc[8];
    for (int i = 0; i < 8; ++i) oacc[i] = (f32x4){0.f, 0.f, 0.f, 0.f};

    const int ktmax = q0 >> 6;
    for (int kt = 0; kt <= ktmax; ++kt) {
        const int kvbase = kt * 64;
        __syncthreads();
        for (int i = 0; i < 4; ++i) {
            const int c  = i * 256 + tid;
            const int kv = c >> 4;
            const int d0 = (c & 15) * 8;
            *(bf16x8*)(&Ks[kv][d0]) = *(const bf16x8*)(
                k + (((size_t)(b * Tc + kvbase + kv)) * KHc + kh) * Dc + d0);
        }
        {
            const int kv = tid & 63;
            const int g0 = (tid >> 6) * 4;
            for (int g = g0; g < g0 + 4; ++g) {
                const int d0 = g * 8;
                const short8 tmp = *(const short8*)(
                    v + (((size_t)(b * Tc + kvbase + kv)) * KHc + kh) * Dc + d0);
                for (int j = 0; j < 8; ++j)
                    Vs[d0 + j][kv] = (unsigned short)tmp[j];
            }
        }
        if (tid < 64) msk[tid] = mask[b * Tc + kvbase + tid];
        __syncthreads();

        f32x4 sacc[4];
        for (int nt = 0; nt < 4; ++nt) sacc[nt] = (f32x4){0.f, 0.f, 0.f, 0.f};
        for (int nt = 0; nt < 4; ++nt)
            for (int kk = 0; kk < 4; ++kk) {
                const bf16x8 kf = *(const bf16x8*)(&Ks[nt * 16 + l15][kk * 32 + quad * 8]);
                sacc[nt] = __builtin_amdgcn_mfma_f32_16x16x32_bf16(
                    qf[kk], kf, sacc[nt], 0, 0, 0);
            }

        float tmax[4] = {MASKVAL, MASKVAL, MASKVAL, MASKVAL};
        for (int nt = 0; nt < 4; ++nt) {
            const int kvpos  = kvbase + nt * 16 + l15;
            const bool kvld  = (msk[nt * 16 + l15] != 0);
            for (int r = 0; r < 4; ++r) {
                const int qr = q0 + wave * 16 + quad * 4 + r;
                float s = sacc[nt][r] * scale;
                s = (kvld && kvpos <= qr) ? s : MASKVAL;
                sacc[nt][r] = s;
                tmax[r] = fmaxf(tmax[r], s);
            }
        }
        for (int r = 0; r < 4; ++r)
            for (int off = 1; off < 16; off <<= 1)
                tmax[r] = fmaxf(tmax[r], __shfl_xor(tmax[r], off, 64));

        float alpha[4];
        for (int r = 0; r < 4; ++r) {
            const float mnew = fmaxf(mrow[r], tmax[r]);
            alpha[r] = __expf(mrow[r] - mnew);
            mrow[r]  = mnew;
        }
        float tsum[4] = {0.f, 0.f, 0.f, 0.f};
        for (int nt = 0; nt < 4; ++nt)
            for (int r = 0; r < 4; ++r) {
                const float p = __expf(sacc[nt][r] - mrow[r]);
                sacc[nt][r] = p;
                tsum[r] += p;
            }
        for (int r = 0; r < 4; ++r)
            for (int off = 1; off < 16; off <<= 1)
                tsum[r] += __shfl_xor(tsum[r], off, 64);
        for (int r = 0; r < 4; ++r)
            lrow[r] = lrow[r] * alpha[r] + tsum[r];

        for (int nt = 0; nt < 4; ++nt)
            for (int r = 0; r < 4; ++r) {
                const __hip_bfloat16 pb = __float2bfloat16(sacc[nt][r]);
                Ps[wave][quad * 4 + r][nt * 16 + l15] =
                    *(const unsigned short*)&pb;
            }
        __syncthreads();

        for (int ntd = 0; ntd < 8; ++ntd)
            for (int r = 0; r < 4; ++r) oacc[ntd][r] *= alpha[r];
        bf16x8 pa[2];
        for (int kk2 = 0; kk2 < 2; ++kk2)
            pa[kk2] = *(const bf16x8*)(&Ps[wave][l15][kk2 * 32 + quad * 8]);
        for (int ntd = 0; ntd < 8; ++ntd)
            for (int kk2 = 0; kk2 < 2; ++kk2) {
                const bf16x8 vf = *(const bf16x8*)(
                    &Vs[ntd * 16 + l15][kk2 * 32 + quad * 8]);
                oacc[ntd] = __builtin_amdgcn_mfma_f32_16x16x32_bf16(
                    pa[kk2], vf, oacc[ntd], 0, 0, 0);
            }
    }

    for (int ntd = 0; ntd < 8; ++ntd)
        for (int r = 0; r < 4; ++r) {
            const float li = lrow[r];
            const float o  = (li > 0.f) ? oacc[ntd][r] / li : 0.f;
            const int qr   = q0 + wave * 16 + quad * 4 + r;
            out[(((size_t)(b * Tc + qr)) * QHc + h) * Dc + ntd * 16 + l15] =
                __float2bfloat16(o);
        }
}

// ---------------------------------------------------------------------------
extern "C" void kernel_launch(void* const* d_in, const int* in_sizes, int n_in,
                              void* d_out, int out_size, void* d_ws, size_t ws_size,
                              hipStream_t stream) {
    const float* x          = (const float*)d_in[0];
    const float* sinp       = (const float*)d_in[1];
    const float* cosp       = (const float*)d_in[2];
    const int*   token_mask = (const int*)d_in[3];
    const float* pre_gamma  = (const float*)d_in[5];
    const float* wq         = (const float*)d_in[6];
    const float* wk         = (const float*)d_in[7];
    const float* wv         = (const float*)d_in[8];
    const float* q_gamma    = (const float*)d_in[9];
    const float* k_gamma    = (const float*)d_in[10];
    const float* wo         = (const float*)d_in[11];
    const float* post_gamma = (const float*)d_in[12];
    const float* wg         = (const float*)d_in[13];
    const float* wu         = (const float*)d_in[14];
    const float* wd         = (const float*)d_in[15];

    // d_out sections, ALL FLOAT32: x | k | v
    float* outx = (float*)d_out;
    float* outk = outx + (size_t)Bc * Tc * Hc;
    float* outv = outk + (size_t)Bc * Tc * KHc * Dc;

    const bool fast = (ws_size >= 176160768ull);

    if (fast) {
        // ---- fast path: bf16 transposed weights in ws -----------------------
        char* w = (char*)d_ws;
        __hip_bfloat16* wq_t  = (__hip_bfloat16*)(w);               //  8.39 MB
        __hip_bfloat16* wk_t  = (__hip_bfloat16*)(w + 8388608);     //  4.19 MB
        __hip_bfloat16* wv_t  = (__hip_bfloat16*)(w + 12582912);    //  4.19 MB
        __hip_bfloat16* wo_t  = (__hip_bfloat16*)(w + 16777216);    //  8.39 MB
        __hip_bfloat16* wg_t  = (__hip_bfloat16*)(w + 25165824);    // 33.55 MB
        __hip_bfloat16* wu_t  = (__hip_bfloat16*)(w + 58720256);    // 33.55 MB
        __hip_bfloat16* wd_t  = (__hip_bfloat16*)(w + 92274688);    // 33.55 MB
        __hip_bfloat16* xnorm = (__hip_bfloat16*)(w + 125829120);   // 16.78 MB
        __hip_bfloat16* qbuf  = (__hip_bfloat16*)(w + 142606336);   // 16.78 MB
        __hip_bfloat16* kbuf  = (__hip_bfloat16*)(w + 159383552);   //  8.39 MB
        __hip_bfloat16* vbuf  = (__hip_bfloat16*)(w + 167772160);   //  8.39 MB
        __hip_bfloat16* Gtmp  = qbuf;

        // 0. convert+transpose all weights (f32 [K][N] -> bf16 [N][K])
        convert_transpose_kernel<<<dim3(Hc/32, Hc/32), 256, 0, stream>>>(wq, wq_t, Hc, Hc);
        convert_transpose_kernel<<<dim3((KHc*Dc)/32, Hc/32), 256, 0, stream>>>(wk, wk_t, Hc, KHc*Dc);
        convert_transpose_kernel<<<dim3((KHc*Dc)/32, Hc/32), 256, 0, stream>>>(wv, wv_t, Hc, KHc*Dc);
        convert_transpose_kernel<<<dim3(Hc/32, Hc/32), 256, 0, stream>>>(wo, wo_t, Hc, Hc);
        convert_transpose_kernel<<<dim3(Fc/32, Hc/32), 256, 0, stream>>>(wg, wg_t, Hc, Fc);
        convert_transpose_kernel<<<dim3(Fc/32, Hc/32), 256, 0, stream>>>(wu, wu_t, Hc, Fc);
        convert_transpose_kernel<<<dim3(Hc/32, Fc/32), 256, 0, stream>>>(wd, wd_t, Fc, Hc);

        // 1. pre-RMSNorm
        rmsnorm_f32_kernel<<<Mc, 256, 0, stream>>>(x, pre_gamma, xnorm, Hc);

        // 2-4. QKV projections
        gemm_bt_kernel<<<dim3(Hc/128, Mc/128), 256, 0, stream>>>(
            xnorm, wq_t, qbuf, nullptr, nullptr, nullptr, Mc, Hc, Hc, Hc, Hc, 0);
        gemm_bt_kernel<<<dim3((KHc*Dc)/128, Mc/128), 256, 0, stream>>>(
            xnorm, wk_t, kbuf, nullptr, nullptr, nullptr, Mc, KHc*Dc, Hc, Hc, Hc, 0);
        gemm_bt_kernel<<<dim3((KHc*Dc)/128, Mc/128), 256, 0, stream>>>(
            xnorm, wv_t, vbuf, outv, nullptr, nullptr, Mc, KHc*Dc, Hc, Hc, Hc, 4);

        // 5-6. per-head RMSNorm + RoPE
        qknorm_rope_kernel<<<Mc*QHc, 128, 0, stream>>>(
            qbuf, q_gamma, sinp, cosp, qbuf, nullptr, QHc);
        qknorm_rope_kernel<<<Mc*KHc, 128, 0, stream>>>(
            kbuf, k_gamma, sinp, cosp, kbuf, outk, KHc);

        // 7. MFMA flash attention
        flash_attn_kernel<<<dim3(Tc/64, Bc*QHc), 256, 0, stream>>>(
            qbuf, kbuf, vbuf, token_mask, qbuf);

        // 8. wo projection + residual -> outx
        gemm_bt_kernel<<<dim3(Hc/128, Mc/128), 256, 0, stream>>>(
            qbuf, wo_t, nullptr, outx, x, nullptr, Mc, Hc, Hc, Hc, Hc, 1);

        // 9. post-RMSNorm
        rmsnorm_f32_kernel<<<Mc, 256, 0, stream>>>(outx, post_gamma, xnorm, Hc);

        // 10. MLP in 4 F-chunks of 2048
        for (int c = 0; c < 4; ++c) {
            const __hip_bfloat16* wg_c = wg_t + (size_t)c * FCHUNK * Hc; // rows
            const __hip_bfloat16* wu_c = wu_t + (size_t)c * FCHUNK * Hc; // rows
            const __hip_bfloat16* wd_c = wd_t + (size_t)c * FCHUNK;      // cols
            gemm_bt_kernel<<<dim3(FCHUNK/128, Mc/128), 256, 0, stream>>>(
                xnorm, wg_c, Gtmp, nullptr, nullptr, nullptr,
                Mc, FCHUNK, Hc, Hc, Hc, 0);
            gemm_bt_kernel<<<dim3(FCHUNK/128, Mc/128), 256, 0, stream>>>(
                xnorm, wu_c, Gtmp, nullptr, nullptr, Gtmp,
                Mc, FCHUNK, Hc, Hc, Hc, 3);
            gemm_bt_kernel<<<dim3(Hc/128, Mc/128), 256, 0, stream>>>(
                Gtmp, wd_c, nullptr, outx, outx, nullptr,
                Mc, Hc, FCHUNK, FCHUNK, Fc, 1);
        }
    } else {
        // ---- fallback: round-4 path (48 MB ws) ------------------------------
        char* w = (char*)d_ws;
        __hip_bfloat16* xnorm = (__hip_bfloat16*)(w);
        __hip_bfloat16* qbuf  = (__hip_bfloat16*)(w + 16777216);
        __hip_bfloat16* kbuf  = (__hip_bfloat16*)(w + 33554432);
        __hip_bfloat16* vbuf  = (__hip_bfloat16*)(w + 41943040);
        __hip_bfloat16* Gtmp  = qbuf;

        rmsnorm_f32_kernel<<<Mc, 256, 0, stream>>>(x, pre_gamma, xnorm, Hc);
        gemm_kernel<<<dim3(Hc/128, Mc/128), 256, 0, stream>>>(
            xnorm, wq, qbuf, nullptr, nullptr, nullptr, Mc, Hc, Hc, Hc, 0);
        gemm_kernel<<<dim3((KHc*Dc)/128, Mc/128), 256, 0, stream>>>(
            xnorm, wk, kbuf, nullptr, nullptr, nullptr, Mc, KHc*Dc, Hc, KHc*Dc, 0);
        gemm_kernel<<<dim3((KHc*Dc)/128, Mc/128), 256, 0, stream>>>(
            xnorm, wv, vbuf, outv, nullptr, nullptr, Mc, KHc*Dc, Hc, KHc*Dc, 4);
        qknorm_rope_kernel<<<Mc*QHc, 128, 0, stream>>>(
            qbuf, q_gamma, sinp, cosp, qbuf, nullptr, QHc);
        qknorm_rope_kernel<<<Mc*KHc, 128, 0, stream>>>(
            kbuf, k_gamma, sinp, cosp, kbuf, outk, KHc);
        flash_attn_kernel<<<dim3(Tc/64, Bc*QHc), 256, 0, stream>>>(
            qbuf, kbuf, vbuf, token_mask, qbuf);
        gemm_kernel<<<dim3(Hc/128, Mc/128), 256, 0, stream>>>(
            qbuf, wo, nullptr, outx, x, nullptr, Mc, Hc, Hc, Hc, 1);
        rmsnorm_f32_kernel<<<Mc, 256, 0, stream>>>(outx, post_gamma, xnorm, Hc);
        for (int c = 0; c < 4; ++c) {
            const float* wg_c = wg + (size_t)c * FCHUNK;
            const float* wu_c = wu + (size_t)c * FCHUNK;
            const float* wd_c = wd + (size_t)c * FCHUNK * Hc;
            gemm_kernel<<<dim3(FCHUNK/128, Mc/128), 256, 0, stream>>>(
                xnorm, wg_c, Gtmp, nullptr, nullptr, nullptr, Mc, FCHUNK, Hc, Fc, 0);
            gemm_kernel<<<dim3(FCHUNK/128, Mc/128), 256, 0, stream>>>(
                xnorm, wu_c, Gtmp, nullptr, nullptr, Gtmp, Mc, FCHUNK, Hc, Fc, 3);
            gemm_kernel<<<dim3(Hc/128, Mc/128), 256, 0, stream>>>(
                Gtmp, wd_c, nullptr, outx, outx, nullptr, Mc, Hc, FCHUNK, Hc, 1);
        }
    }
}